// Round 1
// baseline (1904.713 us; speedup 1.0000x reference)
//
#include <hip/hip_runtime.h>
#include <math.h>

#define ATOM_FEA 128
#define NBR_FEA  64
#define IN_DIM   320   // 2*ATOM_FEA + NBR_FEA
#define OUT_DIM  256   // 2*ATOM_FEA

__device__ __forceinline__ float softplusf(float v) {
    // stable log1p(exp(v))
    return fmaxf(v, 0.f) + log1pf(expf(-fabsf(v)));
}
__device__ __forceinline__ float sigmoidf(float v) {
    return 1.f / (1.f + expf(-v));
}

// ---------------------------------------------------------------------------
// K1: A[n,c] = sum_k W[c,k]      * x[n,k]   (c in [0,256))
//     B[n,c] = sum_k W[c,128+k]  * x[n,k]
// Tiled fp32 GEMM: 64 nodes x 64 outs per block, K=128 in 2 chunks of 64.
// ---------------------------------------------------------------------------
__global__ __launch_bounds__(256) void k1_nodegemm(
    const float* __restrict__ x, const float* __restrict__ W,
    float* __restrict__ A, float* __restrict__ B, int nNodes)
{
    __shared__ float sx[64][68];   // [node][k]  (pad 68 -> 16B-aligned rows)
    __shared__ float sw[64][68];   // [k][out]   transposed W chunk
    const int tx = threadIdx.x & 15;   // out quad
    const int ty = threadIdx.x >> 4;   // node quad
    const int cTile = blockIdx.x * 64;             // 0..511 (A outs then B outs)
    const int nTile = blockIdx.y * 64;
    const int rBase = (cTile < 256) ? cTile : (cTile - 256);
    const int kBase = (cTile < 256) ? 0 : 128;

    float acc[4][4] = {};

    for (int kc = 0; kc < 2; ++kc) {
        int idx = threadIdx.x;
        #pragma unroll
        for (int i = 0; i < 4; ++i, idx += 256) {   // 1024 float4: x chunk
            int n = idx >> 4, q = idx & 15;
            float4 v = make_float4(0.f, 0.f, 0.f, 0.f);
            int gn = nTile + n;
            if (gn < nNodes)
                v = *(const float4*)(x + (size_t)gn * ATOM_FEA + kc * 64 + q * 4);
            *(float4*)(&sx[n][q * 4]) = v;
        }
        idx = threadIdx.x;
        #pragma unroll
        for (int i = 0; i < 4; ++i, idx += 256) {   // 1024 float4: W chunk (transpose)
            int c = idx >> 4, q = idx & 15;
            float4 v = *(const float4*)(W + (size_t)(rBase + c) * IN_DIM + kBase + kc * 64 + q * 4);
            sw[q * 4 + 0][c] = v.x; sw[q * 4 + 1][c] = v.y;
            sw[q * 4 + 2][c] = v.z; sw[q * 4 + 3][c] = v.w;
        }
        __syncthreads();
        #pragma unroll
        for (int k = 0; k < 64; k += 2) {
            float4 w0 = *(const float4*)(&sw[k][tx * 4]);
            float4 w1 = *(const float4*)(&sw[k + 1][tx * 4]);
            float2 xv[4];
            #pragma unroll
            for (int i = 0; i < 4; ++i)
                xv[i] = *(const float2*)(&sx[ty * 4 + i][k]);
            #pragma unroll
            for (int i = 0; i < 4; ++i) {
                acc[i][0] = fmaf(xv[i].x, w0.x, fmaf(xv[i].y, w1.x, acc[i][0]));
                acc[i][1] = fmaf(xv[i].x, w0.y, fmaf(xv[i].y, w1.y, acc[i][1]));
                acc[i][2] = fmaf(xv[i].x, w0.z, fmaf(xv[i].y, w1.z, acc[i][2]));
                acc[i][3] = fmaf(xv[i].x, w0.w, fmaf(xv[i].y, w1.w, acc[i][3]));
            }
        }
        __syncthreads();
    }
    float* dst = (cTile < 256) ? A : B;
    const int cOff = (cTile < 256) ? cTile : (cTile - 256);
    #pragma unroll
    for (int i = 0; i < 4; ++i) {
        int gn = nTile + ty * 4 + i;
        if (gn < nNodes) {
            float4 v = make_float4(acc[i][0], acc[i][1], acc[i][2], acc[i][3]);
            *(float4*)(dst + (size_t)gn * 256 + cOff + tx * 4) = v;
        }
    }
}

// ---------------------------------------------------------------------------
// K2: BN1 statistics. thread = channel c (256). Block owns a contiguous edge
// chunk; per-edge gated value recomputed as A[nbr]+B[src]+We*ea+b.
// Writes per-block partial sum/sumsq (no atomics, no init needed).
// ---------------------------------------------------------------------------
__global__ __launch_bounds__(256) void k2_bn1stats(
    const float* __restrict__ A, const float* __restrict__ Bm,
    const float* __restrict__ ea, const int* __restrict__ ei,
    const float* __restrict__ W, const float* __restrict__ bvec,
    float* __restrict__ part, int nEdges, int chunk)
{
    const int c = threadIdx.x;
    float w[64];
    #pragma unroll
    for (int k = 0; k < 64; ++k) w[k] = W[(size_t)c * IN_DIM + 2 * ATOM_FEA + k];
    const float bc = bvec[c];
    float s = 0.f, s2 = 0.f;
    const int e0 = blockIdx.x * chunk;
    const int e1 = min(e0 + chunk, nEdges);
    for (int e = e0; e < e1; ++e) {
        int src = ei[e];
        int nbr = ei[nEdges + e];
        float g0 = A[(size_t)nbr * 256 + c] + bc;
        float g1 = Bm[(size_t)src * 256 + c];
        const float* eaRow = ea + (size_t)e * 64;   // wave-uniform address
        #pragma unroll
        for (int k = 0; k < 64; k += 8) {
            float4 va = *(const float4*)(eaRow + k);
            float4 vb = *(const float4*)(eaRow + k + 4);
            g0 = fmaf(w[k + 0], va.x, g0); g0 = fmaf(w[k + 1], va.y, g0);
            g0 = fmaf(w[k + 2], va.z, g0); g0 = fmaf(w[k + 3], va.w, g0);
            g1 = fmaf(w[k + 4], vb.x, g1); g1 = fmaf(w[k + 5], vb.y, g1);
            g1 = fmaf(w[k + 6], vb.z, g1); g1 = fmaf(w[k + 7], vb.w, g1);
        }
        float g = g0 + g1;
        s += g;
        s2 = fmaf(g, g, s2);
    }
    part[(size_t)blockIdx.x * 512 + c] = s;
    part[(size_t)blockIdx.x * 512 + 256 + c] = s2;
}

__global__ __launch_bounds__(256) void k2b_reduce(
    const float* __restrict__ part, const float* __restrict__ g1v,
    const float* __restrict__ b1v, float* __restrict__ stats,
    int nBlocks, float invE)
{
    const int c = threadIdx.x;
    float sa = 0.f, sb = 0.f, s2a = 0.f, s2b = 0.f;
    for (int i = 0; i < nBlocks; i += 2) {
        sa  += part[(size_t)i * 512 + c];
        s2a += part[(size_t)i * 512 + 256 + c];
        sb  += part[(size_t)(i + 1) * 512 + c];
        s2b += part[(size_t)(i + 1) * 512 + 256 + c];
    }
    float s = sa + sb, s2 = s2a + s2b;
    float mean = s * invE;
    float var = fmaf(-mean, mean, s2 * invE);
    float sc = g1v[c] * rsqrtf(var + 1e-5f);
    stats[c] = sc;                       // scale
    stats[256 + c] = fmaf(-mean, sc, b1v[c]);  // shift
}

// ---------------------------------------------------------------------------
// K3: recompute gated, apply BN1 affine, msg = sigmoid(filter)*softplus(core),
// sum 12 edges per node. thread = channel (256). Core half (c>=128) publishes
// softplus via double-buffered LDS, 1 barrier/edge. Also BN2 partials.
// ---------------------------------------------------------------------------
__global__ __launch_bounds__(256) void k3_msg(
    const float* __restrict__ A, const float* __restrict__ Bm,
    const float* __restrict__ ea, const int* __restrict__ ei,
    const float* __restrict__ W, const float* __restrict__ bvec,
    const float* __restrict__ stats, float* __restrict__ nbr_sumed,
    float* __restrict__ part2, int nNodes, int nEdges)
{
    __shared__ float sp[2][128];
    const int c = threadIdx.x;
    float w[64];
    #pragma unroll
    for (int k = 0; k < 64; ++k) w[k] = W[(size_t)c * IN_DIM + 2 * ATOM_FEA + k];
    const float bc  = bvec[c];
    const float sc1 = stats[c];
    const float sh1 = stats[256 + c];
    float ps = 0.f, ps2 = 0.f;
    for (int n = blockIdx.x; n < nNodes; n += gridDim.x) {
        float acc = 0.f;
        for (int j = 0; j < 12; ++j) {
            int e = n * 12 + j;
            int src = ei[e];
            int nbr = ei[nEdges + e];
            float g0 = A[(size_t)nbr * 256 + c] + bc;
            float g1 = Bm[(size_t)src * 256 + c];
            const float* eaRow = ea + (size_t)e * 64;   // wave-uniform
            #pragma unroll
            for (int k = 0; k < 64; k += 8) {
                float4 va = *(const float4*)(eaRow + k);
                float4 vb = *(const float4*)(eaRow + k + 4);
                g0 = fmaf(w[k + 0], va.x, g0); g0 = fmaf(w[k + 1], va.y, g0);
                g0 = fmaf(w[k + 2], va.z, g0); g0 = fmaf(w[k + 3], va.w, g0);
                g1 = fmaf(w[k + 4], vb.x, g1); g1 = fmaf(w[k + 5], vb.y, g1);
                g1 = fmaf(w[k + 6], vb.z, g1); g1 = fmaf(w[k + 7], vb.w, g1);
            }
            float g = fmaf(g0 + g1, sc1, sh1);
            if (c >= 128) sp[j & 1][c - 128] = softplusf(g);
            __syncthreads();
            if (c < 128) acc = fmaf(sigmoidf(g), sp[j & 1][c], acc);
        }
        if (c < 128) {
            nbr_sumed[(size_t)n * 128 + c] = acc;
            ps += acc;
            ps2 = fmaf(acc, acc, ps2);
        }
    }
    if (c < 128) {
        part2[(size_t)blockIdx.x * 256 + c] = ps;
        part2[(size_t)blockIdx.x * 256 + 128 + c] = ps2;
    }
}

__global__ __launch_bounds__(128) void k3b_reduce(
    const float* __restrict__ part2, const float* __restrict__ g2v,
    const float* __restrict__ b2v, float* __restrict__ stats2,
    int nBlocks, float invN)
{
    const int c = threadIdx.x;
    float sa = 0.f, sb = 0.f, s2a = 0.f, s2b = 0.f;
    for (int i = 0; i < nBlocks; i += 2) {
        sa  += part2[(size_t)i * 256 + c];
        s2a += part2[(size_t)i * 256 + 128 + c];
        sb  += part2[(size_t)(i + 1) * 256 + c];
        s2b += part2[(size_t)(i + 1) * 256 + 128 + c];
    }
    float s = sa + sb, s2 = s2a + s2b;
    float mean = s * invN;
    float var = fmaf(-mean, mean, s2 * invN);
    float sc = g2v[c] * rsqrtf(var + 1e-5f);
    stats2[c] = sc;
    stats2[128 + c] = fmaf(-mean, sc, b2v[c]);
}

// ---------------------------------------------------------------------------
// K4: out = softplus(x + nbr_sumed*scale2 + shift2), float4 elementwise.
// ---------------------------------------------------------------------------
__global__ __launch_bounds__(256) void k4_final(
    const float* __restrict__ x, const float* __restrict__ ns,
    const float* __restrict__ stats2, float* __restrict__ out, int total4)
{
    int idx = blockIdx.x * 256 + threadIdx.x;
    for (int i = idx; i < total4; i += gridDim.x * 256) {
        int cq = i & 31;   // float4 index within the 128-wide row
        float4 xv = ((const float4*)x)[i];
        float4 sv = ((const float4*)ns)[i];
        float4 sc = ((const float4*)stats2)[cq];
        float4 sh = ((const float4*)(stats2 + 128))[cq];
        float4 o;
        o.x = softplusf(fmaf(sv.x, sc.x, sh.x) + xv.x);
        o.y = softplusf(fmaf(sv.y, sc.y, sh.y) + xv.y);
        o.z = softplusf(fmaf(sv.z, sc.z, sh.z) + xv.z);
        o.w = softplusf(fmaf(sv.w, sc.w, sh.w) + xv.w);
        ((float4*)out)[i] = o;
    }
}

extern "C" void kernel_launch(void* const* d_in, const int* in_sizes, int n_in,
                              void* d_out, int out_size, void* d_ws, size_t ws_size,
                              hipStream_t stream)
{
    const float* x   = (const float*)d_in[0];
    const int*   ei  = (const int*)d_in[1];   // [2][E] int32
    const float* ea  = (const float*)d_in[2];
    const float* W   = (const float*)d_in[3];
    const float* b   = (const float*)d_in[4];
    const float* g1v = (const float*)d_in[5];
    const float* b1v = (const float*)d_in[6];
    const float* g2v = (const float*)d_in[7];
    const float* b2v = (const float*)d_in[8];
    float* out = (float*)d_out;

    const int nNodes = in_sizes[0] / ATOM_FEA;
    const int nEdges = in_sizes[1] / 2;

    const int NB2 = 1024;   // k2 blocks
    const int NB3 = 1024;   // k3 blocks

    float* ws = (float*)d_ws;
    float* A   = ws;                               // nNodes*256
    float* Bm  = A   + (size_t)nNodes * 256;       // nNodes*256
    float* NS  = Bm  + (size_t)nNodes * 256;       // nNodes*128
    float* P1  = NS  + (size_t)nNodes * 128;       // NB2*512
    float* P2  = P1  + (size_t)NB2 * 512;          // NB3*256
    float* S1  = P2  + (size_t)NB3 * 256;          // 512
    float* S2  = S1  + 512;                        // 256
    (void)ws_size; (void)n_in; (void)out_size;

    dim3 grid1(8, (nNodes + 63) / 64);
    k1_nodegemm<<<grid1, 256, 0, stream>>>(x, W, A, Bm, nNodes);

    int chunk = (nEdges + NB2 - 1) / NB2;
    k2_bn1stats<<<NB2, 256, 0, stream>>>(A, Bm, ea, ei, W, b, P1, nEdges, chunk);
    k2b_reduce<<<1, 256, 0, stream>>>(P1, g1v, b1v, S1, NB2, 1.f / (float)nEdges);
    k3_msg<<<NB3, 256, 0, stream>>>(A, Bm, ea, ei, W, b, S1, NS, P2, nNodes, nEdges);
    k3b_reduce<<<1, 128, 0, stream>>>(P2, g2v, b2v, S2, NB3, 1.f / (float)nNodes);
    k4_final<<<2048, 256, 0, stream>>>(x, NS, S2, out, nNodes * 32);
}

// Round 2
// 1529.824 us; speedup vs baseline: 1.2451x; 1.2451x over previous
//
#include <hip/hip_runtime.h>
#include <math.h>

#define ATOM_FEA 128
#define NBR_FEA  64
#define IN_DIM   320   // 2*ATOM_FEA + NBR_FEA
#define OUT_DIM  256   // 2*ATOM_FEA

#define M_TILE   48    // edges per tile = exactly 4 nodes (48 = 4*12)
#define GRID_G   1024  // persistent grid for the two edge-GEMM kernels

typedef float  f32x4 __attribute__((ext_vector_type(4)));
typedef short  s16x8 __attribute__((ext_vector_type(8)));   // 8 bf16 in 4 VGPRs

__device__ __forceinline__ float softplusf(float v) {
    return fmaxf(v, 0.f) + log1pf(expf(-fabsf(v)));
}
__device__ __forceinline__ float sigmoidf(float v) {
    return 1.f / (1.f + expf(-v));
}
__device__ __forceinline__ unsigned short f2bf(float f) {   // RNE f32->bf16
    unsigned u = __float_as_uint(f);
    return (unsigned short)((u + 0x7FFFu + ((u >> 16) & 1u)) >> 16);
}
__device__ __forceinline__ float bf2f(unsigned short h) {
    return __uint_as_float(((unsigned)h) << 16);
}
__device__ __forceinline__ unsigned pk2(float a, float b) {
    return (unsigned)f2bf(a) | ((unsigned)f2bf(b) << 16);
}

// LDS layout (shared by k2_gemm / k3_gemm):
//   [0, 6912)        : ea tile, 48 rows x 72 bf16 (stride 144 B, 16B-aligned)
//   [6912, 43776)    : union { Wt 256 rows x 72 bf16 | X exchange 48 x 264 bf16 }
#define EA_OFF   0
#define EA_STR   144
#define WT_OFF   6912
#define WT_STR   144
#define X_OFF    6912
#define X_STR    528   // 264 bf16
#define SMEM_SZ  43776

// ---------------------------------------------------------------------------
// K1: A[n,c] = W[c,0:128]·x[n],  B[n,c] = W[c,128:256]·x[n]   (fp32 tiled)
// ---------------------------------------------------------------------------
__global__ __launch_bounds__(256) void k1_nodegemm(
    const float* __restrict__ x, const float* __restrict__ W,
    float* __restrict__ A, float* __restrict__ B, int nNodes)
{
    __shared__ float sx[64][68];
    __shared__ float sw[64][68];
    const int tx = threadIdx.x & 15;
    const int ty = threadIdx.x >> 4;
    const int cTile = blockIdx.x * 64;
    const int nTile = blockIdx.y * 64;
    const int rBase = (cTile < 256) ? cTile : (cTile - 256);
    const int kBase = (cTile < 256) ? 0 : 128;

    float acc[4][4] = {};
    for (int kc = 0; kc < 2; ++kc) {
        int idx = threadIdx.x;
        #pragma unroll
        for (int i = 0; i < 4; ++i, idx += 256) {
            int n = idx >> 4, q = idx & 15;
            float4 v = make_float4(0.f, 0.f, 0.f, 0.f);
            int gn = nTile + n;
            if (gn < nNodes)
                v = *(const float4*)(x + (size_t)gn * ATOM_FEA + kc * 64 + q * 4);
            *(float4*)(&sx[n][q * 4]) = v;
        }
        idx = threadIdx.x;
        #pragma unroll
        for (int i = 0; i < 4; ++i, idx += 256) {
            int c = idx >> 4, q = idx & 15;
            float4 v = *(const float4*)(W + (size_t)(rBase + c) * IN_DIM + kBase + kc * 64 + q * 4);
            sw[q * 4 + 0][c] = v.x; sw[q * 4 + 1][c] = v.y;
            sw[q * 4 + 2][c] = v.z; sw[q * 4 + 3][c] = v.w;
        }
        __syncthreads();
        #pragma unroll
        for (int k = 0; k < 64; k += 2) {
            float4 w0 = *(const float4*)(&sw[k][tx * 4]);
            float4 w1 = *(const float4*)(&sw[k + 1][tx * 4]);
            float2 xv[4];
            #pragma unroll
            for (int i = 0; i < 4; ++i)
                xv[i] = *(const float2*)(&sx[ty * 4 + i][k]);
            #pragma unroll
            for (int i = 0; i < 4; ++i) {
                acc[i][0] = fmaf(xv[i].x, w0.x, fmaf(xv[i].y, w1.x, acc[i][0]));
                acc[i][1] = fmaf(xv[i].x, w0.y, fmaf(xv[i].y, w1.y, acc[i][1]));
                acc[i][2] = fmaf(xv[i].x, w0.z, fmaf(xv[i].y, w1.z, acc[i][2]));
                acc[i][3] = fmaf(xv[i].x, w0.w, fmaf(xv[i].y, w1.w, acc[i][3]));
            }
        }
        __syncthreads();
    }
    float* dst = (cTile < 256) ? A : B;
    const int cOff = (cTile < 256) ? cTile : (cTile - 256);
    #pragma unroll
    for (int i = 0; i < 4; ++i) {
        int gn = nTile + ty * 4 + i;
        if (gn < nNodes) {
            float4 v = make_float4(acc[i][0], acc[i][1], acc[i][2], acc[i][3]);
            *(float4*)(dst + (size_t)gn * 256 + cOff + tx * 4) = v;
        }
    }
}

// ---------------------------------------------------------------------------
// K2: MFMA edge-GEMM (gated = EA + A[nbr] + B[src] + b) -> BN1 sum/sumsq
// partials. Tile: 48 edges x 256 ch, K=64. 4 waves, each owns 64 channels.
// ---------------------------------------------------------------------------
__global__ __launch_bounds__(256) void k2_gemm(
    const float* __restrict__ A, const float* __restrict__ Bm,
    const float* __restrict__ ea, const int* __restrict__ ei,
    const float* __restrict__ W, const float* __restrict__ bvec,
    float* __restrict__ part, int nEdges)
{
    __shared__ alignas(16) char smem[SMEM_SZ];
    const int tid  = threadIdx.x;
    const int wave = tid >> 6;
    const int lane = tid & 63;
    const int li   = lane & 15;
    const int quad = lane >> 4;

    int chn[4]; float bc[4];
    #pragma unroll
    for (int ns = 0; ns < 4; ++ns) {
        chn[ns] = wave * 64 + ns * 16 + li;
        bc[ns]  = bvec[chn[ns]];
    }

    // stage Wt (We^T rows = W[c][256..320), contiguous) as bf16
    #pragma unroll
    for (int i = 0; i < 16; ++i) {
        int idx = tid + i * 256;        // 0..4095
        int c = idx >> 4, q = idx & 15;
        float4 v = *(const float4*)(W + (size_t)c * IN_DIM + 256 + q * 4);
        uint2 u; u.x = pk2(v.x, v.y); u.y = pk2(v.z, v.w);
        *(uint2*)(smem + WT_OFF + c * WT_STR + q * 8) = u;
    }
    __syncthreads();
    s16x8 bfr[2][4];
    #pragma unroll
    for (int ks = 0; ks < 2; ++ks)
        #pragma unroll
        for (int ns = 0; ns < 4; ++ns)
            bfr[ks][ns] = *(const s16x8*)(smem + WT_OFF + chn[ns] * WT_STR + (ks * 32 + quad * 8) * 2);
    __syncthreads();

    float s[4] = {}, s2[4] = {};
    const int nTiles = (nEdges + M_TILE - 1) / M_TILE;
    for (int t = blockIdx.x; t < nTiles; t += gridDim.x) {
        const int tBase = t * M_TILE;
        // stage ea tile (fp32 -> bf16)
        #pragma unroll
        for (int i = 0; i < 3; ++i) {
            int idx = tid + i * 256;    // 0..767
            int r = idx >> 4, q = idx & 15;
            int ge = tBase + r;
            float4 v = make_float4(0.f, 0.f, 0.f, 0.f);
            if (ge < nEdges) v = *(const float4*)(ea + (size_t)ge * 64 + q * 4);
            uint2 u; u.x = pk2(v.x, v.y); u.y = pk2(v.z, v.w);
            *(uint2*)(smem + EA_OFF + r * EA_STR + q * 8) = u;
        }
        __syncthreads();

        s16x8 af[2][3];
        #pragma unroll
        for (int ks = 0; ks < 2; ++ks)
            #pragma unroll
            for (int ms = 0; ms < 3; ++ms)
                af[ks][ms] = *(const s16x8*)(smem + EA_OFF + (ms * 16 + li) * EA_STR + (ks * 32 + quad * 8) * 2);

        f32x4 acc[3][4] = {};
        #pragma unroll
        for (int ks = 0; ks < 2; ++ks)
            #pragma unroll
            for (int ms = 0; ms < 3; ++ms)
                #pragma unroll
                for (int ns = 0; ns < 4; ++ns)
                    acc[ms][ns] = __builtin_amdgcn_mfma_f32_16x16x32_bf16(
                        af[ks][ms], bfr[ks][ns], acc[ms][ns], 0, 0, 0);

        #pragma unroll
        for (int ms = 0; ms < 3; ++ms)
            #pragma unroll
            for (int r = 0; r < 4; ++r) {
                int e = tBase + ms * 16 + quad * 4 + r;
                if (e < nEdges) {
                    int sn = ei[e];
                    int nb = ei[nEdges + e];
                    const float* Arow = A  + (size_t)nb * 256;
                    const float* Brow = Bm + (size_t)sn * 256;
                    #pragma unroll
                    for (int ns = 0; ns < 4; ++ns) {
                        float g = acc[ms][ns][r] + Arow[chn[ns]] + Brow[chn[ns]] + bc[ns];
                        s[ns] += g;
                        s2[ns] = fmaf(g, g, s2[ns]);
                    }
                }
            }
        __syncthreads();
    }
    #pragma unroll
    for (int ns = 0; ns < 4; ++ns) {
        s[ns]  += __shfl_xor(s[ns], 16);  s[ns]  += __shfl_xor(s[ns], 32);
        s2[ns] += __shfl_xor(s2[ns], 16); s2[ns] += __shfl_xor(s2[ns], 32);
        if (quad == 0) {
            part[(size_t)blockIdx.x * 512 + chn[ns]]       = s[ns];
            part[(size_t)blockIdx.x * 512 + 256 + chn[ns]] = s2[ns];
        }
    }
}

__global__ __launch_bounds__(256) void k2b_reduce(
    const float* __restrict__ part, const float* __restrict__ g1v,
    const float* __restrict__ b1v, float* __restrict__ stats,
    int nBlocks, float invE)
{
    const int c = threadIdx.x;
    float sa = 0.f, sb = 0.f, s2a = 0.f, s2b = 0.f;
    for (int i = 0; i < nBlocks; i += 2) {
        sa  += part[(size_t)i * 512 + c];
        s2a += part[(size_t)i * 512 + 256 + c];
        sb  += part[(size_t)(i + 1) * 512 + c];
        s2b += part[(size_t)(i + 1) * 512 + 256 + c];
    }
    float s = sa + sb, s2 = s2a + s2b;
    float mean = s * invE;
    float var = fmaf(-mean, mean, s2 * invE);
    float sc = g1v[c] * rsqrtf(var + 1e-5f);
    stats[c] = sc;
    stats[256 + c] = fmaf(-mean, sc, b1v[c]);
}

// ---------------------------------------------------------------------------
// K3: MFMA edge-GEMM again -> BN1 affine -> bf16 exchange tile in LDS ->
// msg = sigmoid(filter)*softplus(core) -> exact 12-edge node sums (tile = 4
// nodes) -> NS + BN2 partials.
// ---------------------------------------------------------------------------
__global__ __launch_bounds__(256) void k3_gemm(
    const float* __restrict__ A, const float* __restrict__ Bm,
    const float* __restrict__ ea, const int* __restrict__ ei,
    const float* __restrict__ W, const float* __restrict__ bvec,
    const float* __restrict__ stats, float* __restrict__ NS,
    float* __restrict__ part2, int nNodes, int nEdges)
{
    __shared__ alignas(16) char smem[SMEM_SZ];
    const int tid  = threadIdx.x;
    const int wave = tid >> 6;
    const int lane = tid & 63;
    const int li   = lane & 15;
    const int quad = lane >> 4;

    int chn[4]; float bc[4], sc1[4], sh1[4];
    #pragma unroll
    for (int ns = 0; ns < 4; ++ns) {
        chn[ns] = wave * 64 + ns * 16 + li;
        bc[ns]  = bvec[chn[ns]];
        sc1[ns] = stats[chn[ns]];
        sh1[ns] = stats[256 + chn[ns]];
    }

    #pragma unroll
    for (int i = 0; i < 16; ++i) {
        int idx = tid + i * 256;
        int c = idx >> 4, q = idx & 15;
        float4 v = *(const float4*)(W + (size_t)c * IN_DIM + 256 + q * 4);
        uint2 u; u.x = pk2(v.x, v.y); u.y = pk2(v.z, v.w);
        *(uint2*)(smem + WT_OFF + c * WT_STR + q * 8) = u;
    }
    __syncthreads();
    s16x8 bfr[2][4];
    #pragma unroll
    for (int ks = 0; ks < 2; ++ks)
        #pragma unroll
        for (int ns = 0; ns < 4; ++ns)
            bfr[ks][ns] = *(const s16x8*)(smem + WT_OFF + chn[ns] * WT_STR + (ks * 32 + quad * 8) * 2);
    __syncthreads();   // Wt region is dead now; reused as X exchange tile

    const int msgc  = tid & 127;   // channel for msg phase
    const int slotA = tid >> 7;    // node slots: slotA and slotA+2
    float ps[2] = {}, ps2[2] = {};

    const int nTiles = (nEdges + M_TILE - 1) / M_TILE;
    for (int t = blockIdx.x; t < nTiles; t += gridDim.x) {
        const int tBase = t * M_TILE;
        #pragma unroll
        for (int i = 0; i < 3; ++i) {
            int idx = tid + i * 256;
            int r = idx >> 4, q = idx & 15;
            int ge = tBase + r;
            float4 v = make_float4(0.f, 0.f, 0.f, 0.f);
            if (ge < nEdges) v = *(const float4*)(ea + (size_t)ge * 64 + q * 4);
            uint2 u; u.x = pk2(v.x, v.y); u.y = pk2(v.z, v.w);
            *(uint2*)(smem + EA_OFF + r * EA_STR + q * 8) = u;
        }
        __syncthreads();   // B1

        s16x8 af[2][3];
        #pragma unroll
        for (int ks = 0; ks < 2; ++ks)
            #pragma unroll
            for (int ms = 0; ms < 3; ++ms)
                af[ks][ms] = *(const s16x8*)(smem + EA_OFF + (ms * 16 + li) * EA_STR + (ks * 32 + quad * 8) * 2);

        f32x4 acc[3][4] = {};
        #pragma unroll
        for (int ks = 0; ks < 2; ++ks)
            #pragma unroll
            for (int ms = 0; ms < 3; ++ms)
                #pragma unroll
                for (int ns = 0; ns < 4; ++ns)
                    acc[ms][ns] = __builtin_amdgcn_mfma_f32_16x16x32_bf16(
                        af[ks][ms], bfr[ks][ns], acc[ms][ns], 0, 0, 0);

        #pragma unroll
        for (int ms = 0; ms < 3; ++ms)
            #pragma unroll
            for (int r = 0; r < 4; ++r) {
                int el = ms * 16 + quad * 4 + r;
                int e = tBase + el;
                if (e < nEdges) {
                    int sn = ei[e];
                    int nb = ei[nEdges + e];
                    const float* Arow = A  + (size_t)nb * 256;
                    const float* Brow = Bm + (size_t)sn * 256;
                    #pragma unroll
                    for (int ns = 0; ns < 4; ++ns) {
                        float g = acc[ms][ns][r] + Arow[chn[ns]] + Brow[chn[ns]] + bc[ns];
                        float ga = fmaf(g, sc1[ns], sh1[ns]);
                        *(unsigned short*)(smem + X_OFF + el * X_STR + chn[ns] * 2) = f2bf(ga);
                    }
                }
            }
        __syncthreads();   // B2: X complete

        const int nodeBase = t * 4;
        #pragma unroll
        for (int it = 0; it < 2; ++it) {
            int slot = slotA + it * 2;
            float accm = 0.f;
            #pragma unroll
            for (int j = 0; j < 12; ++j) {
                int row = slot * 12 + j;
                float f = bf2f(*(const unsigned short*)(smem + X_OFF + row * X_STR + msgc * 2));
                float cv = bf2f(*(const unsigned short*)(smem + X_OFF + row * X_STR + (msgc + 128) * 2));
                accm = fmaf(sigmoidf(f), softplusf(cv), accm);
            }
            int node = nodeBase + slot;
            if (node < nNodes) {
                NS[(size_t)node * 128 + msgc] = accm;
                ps[it] += accm;
                ps2[it] = fmaf(accm, accm, ps2[it]);
            }
        }
        __syncthreads();   // B3: X reads done before next tile overwrites
    }
    part2[(size_t)blockIdx.x * 512 + tid]       = ps[0] + ps[1];
    part2[(size_t)blockIdx.x * 512 + 256 + tid] = ps2[0] + ps2[1];
}

__global__ __launch_bounds__(128) void k3b_reduce(
    const float* __restrict__ part2, const float* __restrict__ g2v,
    const float* __restrict__ b2v, float* __restrict__ stats2,
    int nBlocks, float invN)
{
    const int c = threadIdx.x;
    float s = 0.f, s2 = 0.f;
    for (int i = 0; i < nBlocks; ++i) {
        s  += part2[(size_t)i * 512 + c] + part2[(size_t)i * 512 + 128 + c];
        s2 += part2[(size_t)i * 512 + 256 + c] + part2[(size_t)i * 512 + 384 + c];
    }
    float mean = s * invN;
    float var = fmaf(-mean, mean, s2 * invN);
    float sc = g2v[c] * rsqrtf(var + 1e-5f);
    stats2[c] = sc;
    stats2[128 + c] = fmaf(-mean, sc, b2v[c]);
}

// ---------------------------------------------------------------------------
// K4: out = softplus(x + nbr_sumed*scale2 + shift2)
// ---------------------------------------------------------------------------
__global__ __launch_bounds__(256) void k4_final(
    const float* __restrict__ x, const float* __restrict__ ns,
    const float* __restrict__ stats2, float* __restrict__ out, int total4)
{
    int idx = blockIdx.x * 256 + threadIdx.x;
    for (int i = idx; i < total4; i += gridDim.x * 256) {
        int cq = i & 31;
        float4 xv = ((const float4*)x)[i];
        float4 sv = ((const float4*)ns)[i];
        float4 sc = ((const float4*)stats2)[cq];
        float4 sh = ((const float4*)(stats2 + 128))[cq];
        float4 o;
        o.x = softplusf(fmaf(sv.x, sc.x, sh.x) + xv.x);
        o.y = softplusf(fmaf(sv.y, sc.y, sh.y) + xv.y);
        o.z = softplusf(fmaf(sv.z, sc.z, sh.z) + xv.z);
        o.w = softplusf(fmaf(sv.w, sc.w, sh.w) + xv.w);
        ((float4*)out)[i] = o;
    }
}

extern "C" void kernel_launch(void* const* d_in, const int* in_sizes, int n_in,
                              void* d_out, int out_size, void* d_ws, size_t ws_size,
                              hipStream_t stream)
{
    const float* x   = (const float*)d_in[0];
    const int*   ei  = (const int*)d_in[1];
    const float* ea  = (const float*)d_in[2];
    const float* W   = (const float*)d_in[3];
    const float* b   = (const float*)d_in[4];
    const float* g1v = (const float*)d_in[5];
    const float* b1v = (const float*)d_in[6];
    const float* g2v = (const float*)d_in[7];
    const float* b2v = (const float*)d_in[8];
    float* out = (float*)d_out;

    const int nNodes = in_sizes[0] / ATOM_FEA;
    const int nEdges = in_sizes[1] / 2;

    float* ws = (float*)d_ws;
    float* A   = ws;                               // nNodes*256
    float* Bm  = A   + (size_t)nNodes * 256;       // nNodes*256
    float* NS  = Bm  + (size_t)nNodes * 256;       // nNodes*128
    float* P1  = NS  + (size_t)nNodes * 128;       // GRID_G*512
    float* P2  = P1  + (size_t)GRID_G * 512;       // GRID_G*512
    float* S1  = P2  + (size_t)GRID_G * 512;       // 512
    float* S2  = S1  + 512;                        // 256
    (void)ws_size; (void)n_in; (void)out_size;

    dim3 grid1(8, (nNodes + 63) / 64);
    k1_nodegemm<<<grid1, 256, 0, stream>>>(x, W, A, Bm, nNodes);

    k2_gemm<<<GRID_G, 256, 0, stream>>>(A, Bm, ea, ei, W, b, P1, nEdges);
    k2b_reduce<<<1, 256, 0, stream>>>(P1, g1v, b1v, S1, GRID_G, 1.f / (float)nEdges);
    k3_gemm<<<GRID_G, 256, 0, stream>>>(A, Bm, ea, ei, W, b, S1, NS, P2, nNodes, nEdges);
    k3b_reduce<<<1, 128, 0, stream>>>(P2, g2v, b2v, S2, GRID_G, 1.f / (float)nNodes);
    k4_final<<<2048, 256, 0, stream>>>(x, NS, S2, out, nNodes * 32);
}

// Round 3
// 675.266 us; speedup vs baseline: 2.8207x; 2.2655x over previous
//
#include <hip/hip_runtime.h>
#include <math.h>

#define ATOM_FEA 128
#define NBR_FEA  64
#define IN_DIM   320   // 2*ATOM_FEA + NBR_FEA
#define OUT_DIM  256   // 2*ATOM_FEA

#define M_TILE   48    // edges per tile = exactly 4 nodes (48 = 4*12)
#define GRID_G   1024

typedef float  f32x4 __attribute__((ext_vector_type(4)));
typedef short  s16x8 __attribute__((ext_vector_type(8)));   // 8 bf16

__device__ __forceinline__ float softplusf(float v) {
    float e = __expf(-fabsf(v));
    return fmaxf(v, 0.f) + __logf(1.f + e);
}
__device__ __forceinline__ float sigmoidf(float v) {
    return __builtin_amdgcn_rcpf(1.f + __expf(-v));
}
__device__ __forceinline__ unsigned short f2bf(float f) {   // RNE f32->bf16
    unsigned u = __float_as_uint(f);
    return (unsigned short)((u + 0x7FFFu + ((u >> 16) & 1u)) >> 16);
}
__device__ __forceinline__ float bf2f(unsigned short h) {
    return __uint_as_float(((unsigned)h) << 16);
}
__device__ __forceinline__ unsigned pk2(float a, float b) {
    return (unsigned)f2bf(a) | ((unsigned)f2bf(b) << 16);
}

// LDS layout for k2_fused:
//   [0, 6912)        : ea tile, 48 rows x stride 144 B (bf16)
//   [6912, 31872)    : X exchange, 48 rows x stride 520 B (256 bf16 + pad)
//                      520B pad -> quads land on distinct bank octets
#define EA_OFF   0
#define EA_STR   144
#define X_OFF    6912
#define X_STR    520
#define SMEM2    31872

// ---------------------------------------------------------------------------
// K1: A[n,c] = W[c,0:128]·x[n],  B[n,c] = W[c,128:256]·x[n]   (fp32 tiled)
// ---------------------------------------------------------------------------
__global__ __launch_bounds__(256) void k1_nodegemm(
    const float* __restrict__ x, const float* __restrict__ W,
    float* __restrict__ A, float* __restrict__ B, int nNodes)
{
    __shared__ float sx[64][68];
    __shared__ float sw[64][68];
    const int tx = threadIdx.x & 15;
    const int ty = threadIdx.x >> 4;
    const int cTile = blockIdx.x * 64;
    const int nTile = blockIdx.y * 64;
    const int rBase = (cTile < 256) ? cTile : (cTile - 256);
    const int kBase = (cTile < 256) ? 0 : 128;

    float acc[4][4] = {};
    for (int kc = 0; kc < 2; ++kc) {
        int idx = threadIdx.x;
        #pragma unroll
        for (int i = 0; i < 4; ++i, idx += 256) {
            int n = idx >> 4, q = idx & 15;
            float4 v = make_float4(0.f, 0.f, 0.f, 0.f);
            int gn = nTile + n;
            if (gn < nNodes)
                v = *(const float4*)(x + (size_t)gn * ATOM_FEA + kc * 64 + q * 4);
            *(float4*)(&sx[n][q * 4]) = v;
        }
        idx = threadIdx.x;
        #pragma unroll
        for (int i = 0; i < 4; ++i, idx += 256) {
            int c = idx >> 4, q = idx & 15;
            float4 v = *(const float4*)(W + (size_t)(rBase + c) * IN_DIM + kBase + kc * 64 + q * 4);
            sw[q * 4 + 0][c] = v.x; sw[q * 4 + 1][c] = v.y;
            sw[q * 4 + 2][c] = v.z; sw[q * 4 + 3][c] = v.w;
        }
        __syncthreads();
        #pragma unroll
        for (int k = 0; k < 64; k += 2) {
            float4 w0 = *(const float4*)(&sw[k][tx * 4]);
            float4 w1 = *(const float4*)(&sw[k + 1][tx * 4]);
            float2 xv[4];
            #pragma unroll
            for (int i = 0; i < 4; ++i)
                xv[i] = *(const float2*)(&sx[ty * 4 + i][k]);
            #pragma unroll
            for (int i = 0; i < 4; ++i) {
                acc[i][0] = fmaf(xv[i].x, w0.x, fmaf(xv[i].y, w1.x, acc[i][0]));
                acc[i][1] = fmaf(xv[i].x, w0.y, fmaf(xv[i].y, w1.y, acc[i][1]));
                acc[i][2] = fmaf(xv[i].x, w0.z, fmaf(xv[i].y, w1.z, acc[i][2]));
                acc[i][3] = fmaf(xv[i].x, w0.w, fmaf(xv[i].y, w1.w, acc[i][3]));
            }
        }
        __syncthreads();
    }
    float* dst = (cTile < 256) ? A : B;
    const int cOff = (cTile < 256) ? cTile : (cTile - 256);
    #pragma unroll
    for (int i = 0; i < 4; ++i) {
        int gn = nTile + ty * 4 + i;
        if (gn < nNodes) {
            float4 v = make_float4(acc[i][0], acc[i][1], acc[i][2], acc[i][3]);
            *(float4*)(dst + (size_t)gn * 256 + cOff + tx * 4) = v;
        }
    }
}

// ---------------------------------------------------------------------------
// K2: MFMA edge-GEMM (We*ea) -> LDS exchange -> clean-layout epilogue:
// gated = X + A[nbr] + B[node] + b, store bf16 gated, accumulate BN1 partials.
// Tile = 48 edges (4 nodes) x 256 ch. wave <-> node slot in phase 2.
// ---------------------------------------------------------------------------
__global__ __launch_bounds__(256) void k2_fused(
    const float* __restrict__ A, const float* __restrict__ Bm,
    const float* __restrict__ ea, const int* __restrict__ ei,
    const float* __restrict__ W, const float* __restrict__ bvec,
    unsigned short* __restrict__ gated, float* __restrict__ part,
    int nNodes, int nEdges)
{
    __shared__ alignas(16) char smem[SMEM2];
    const int tid  = threadIdx.x;
    const int wave = tid >> 6;
    const int lane = tid & 63;
    const int li   = lane & 15;
    const int quad = lane >> 4;

    // W (We^T) fragments straight from global (once per block), packed bf16
    s16x8 bfr[2][4];
    #pragma unroll
    for (int ks = 0; ks < 2; ++ks)
        #pragma unroll
        for (int ns = 0; ns < 4; ++ns) {
            int chn = wave * 64 + ns * 16 + li;
            const float* wr = W + (size_t)chn * IN_DIM + 256 + ks * 32 + quad * 8;
            float4 va = *(const float4*)wr;
            float4 vb = *(const float4*)(wr + 4);
            union { uint4 u; s16x8 v; } cv;
            cv.u = make_uint4(pk2(va.x, va.y), pk2(va.z, va.w),
                              pk2(vb.x, vb.y), pk2(vb.z, vb.w));
            bfr[ks][ns] = cv.v;
        }

    const int chq = lane;                              // phase-2: ch quad id
    const float4 b4 = *(const float4*)(bvec + chq * 4);
    float4 s4  = {0.f, 0.f, 0.f, 0.f};
    float4 s24 = {0.f, 0.f, 0.f, 0.f};

    const int nTiles = (nEdges + M_TILE - 1) / M_TILE;
    for (int t = blockIdx.x; t < nTiles; t += gridDim.x) {
        const int tBase = t * M_TILE;
        // stage ea tile (fp32 -> bf16)
        #pragma unroll
        for (int i = 0; i < 3; ++i) {
            int idx = tid + i * 256;
            int r = idx >> 4, q = idx & 15;
            int ge = tBase + r;
            float4 v = make_float4(0.f, 0.f, 0.f, 0.f);
            if (ge < nEdges) v = *(const float4*)(ea + (size_t)ge * 64 + q * 4);
            uint2 u; u.x = pk2(v.x, v.y); u.y = pk2(v.z, v.w);
            *(uint2*)(smem + EA_OFF + r * EA_STR + q * 8) = u;
        }
        __syncthreads();   // B1 (also fences prev-iter X reads)

        s16x8 af[2][3];
        #pragma unroll
        for (int ks = 0; ks < 2; ++ks)
            #pragma unroll
            for (int ms = 0; ms < 3; ++ms)
                af[ks][ms] = *(const s16x8*)(smem + EA_OFF + (ms * 16 + li) * EA_STR + (ks * 32 + quad * 8) * 2);

        f32x4 acc[3][4] = {};
        #pragma unroll
        for (int ks = 0; ks < 2; ++ks)
            #pragma unroll
            for (int ms = 0; ms < 3; ++ms)
                #pragma unroll
                for (int ns = 0; ns < 4; ++ns)
                    acc[ms][ns] = __builtin_amdgcn_mfma_f32_16x16x32_bf16(
                        af[ks][ms], bfr[ks][ns], acc[ms][ns], 0, 0, 0);

        // dump MFMA result to exchange tile (bf16)
        #pragma unroll
        for (int ms = 0; ms < 3; ++ms)
            #pragma unroll
            for (int ns = 0; ns < 4; ++ns) {
                int col = wave * 64 + ns * 16 + li;
                #pragma unroll
                for (int r = 0; r < 4; ++r) {
                    int row = ms * 16 + quad * 4 + r;
                    *(unsigned short*)(smem + X_OFF + row * X_STR + col * 2) = f2bf(acc[ms][ns][r]);
                }
            }
        __syncthreads();   // B2

        // phase 2: wave owns node (t*4 + wave); lanes cover 256 ch as float4
        const int node = t * 4 + wave;
        if (node < nNodes) {
            const float4 Bn = *(const float4*)(Bm + (size_t)node * 256 + chq * 4);
            const int e0 = tBase + wave * 12;
            #pragma unroll
            for (int j = 0; j < 12; ++j) {
                const int e = e0 + j;
                const int nb = ei[nEdges + e];   // wave-uniform
                float4 a4 = *(const float4*)(A + (size_t)nb * 256 + chq * 4);
                uint2 xv = *(const uint2*)(smem + X_OFF + (wave * 12 + j) * X_STR + chq * 8);
                float g0 = bf2f((unsigned short)(xv.x & 0xffffu)) + a4.x + Bn.x + b4.x;
                float g1 = bf2f((unsigned short)(xv.x >> 16))     + a4.y + Bn.y + b4.y;
                float g2 = bf2f((unsigned short)(xv.y & 0xffffu)) + a4.z + Bn.z + b4.z;
                float g3 = bf2f((unsigned short)(xv.y >> 16))     + a4.w + Bn.w + b4.w;
                s4.x += g0; s4.y += g1; s4.z += g2; s4.w += g3;
                s24.x = fmaf(g0, g0, s24.x); s24.y = fmaf(g1, g1, s24.y);
                s24.z = fmaf(g2, g2, s24.z); s24.w = fmaf(g3, g3, s24.w);
                uint2 o; o.x = pk2(g0, g1); o.y = pk2(g2, g3);
                *(uint2*)(gated + (size_t)e * 256 + chq * 4) = o;
            }
        }
        // no barrier here: next-iter B1 fences X overwrite
    }

    // block-level BN1 partial reduce (channels shared across the 4 waves)
    __syncthreads();
    float* red = (float*)smem;
    *(float4*)(red + (size_t)(wave * 64 + chq) * 8)     = s4;
    *(float4*)(red + (size_t)(wave * 64 + chq) * 8 + 4) = s24;
    __syncthreads();
    {
        const int c = tid;          // channel 0..255
        const int g = c >> 2, k = c & 3;
        float s = 0.f, s2 = 0.f;
        #pragma unroll
        for (int w = 0; w < 4; ++w) {
            s  += red[(w * 64 + g) * 8 + k];
            s2 += red[(w * 64 + g) * 8 + 4 + k];
        }
        part[(size_t)blockIdx.x * 512 + c]       = s;
        part[(size_t)blockIdx.x * 512 + 256 + c] = s2;
    }
}

__global__ __launch_bounds__(1024) void k2b_reduce(
    const float* __restrict__ part, const float* __restrict__ g1v,
    const float* __restrict__ b1v, float* __restrict__ stats,
    int nBlocks, float invE)
{
    __shared__ float4 red[8][128];
    const int cq = threadIdx.x & 127;
    const int g  = threadIdx.x >> 7;
    float4 s = {0.f, 0.f, 0.f, 0.f};
    for (int i = g; i < nBlocks; i += 8) {
        float4 v = *(const float4*)(part + (size_t)i * 512 + cq * 4);
        s.x += v.x; s.y += v.y; s.z += v.z; s.w += v.w;
    }
    red[g][cq] = s;
    __syncthreads();
    if (threadIdx.x < 256) {
        const int c = threadIdx.x;
        float sT = 0.f, s2T = 0.f;
        #pragma unroll
        for (int w = 0; w < 8; ++w) {
            const float* r = (const float*)&red[w][0];
            sT  += r[c];
            s2T += r[256 + c];
        }
        float mean = sT * invE;
        float var = fmaf(-mean, mean, s2T * invE);
        float sc = g1v[c] * rsqrtf(var + 1e-5f);
        stats[c] = sc;
        stats[256 + c] = fmaf(-mean, sc, b1v[c]);
    }
}

// ---------------------------------------------------------------------------
// K3: elementwise over stored bf16 gated: BN1 affine -> sigmoid*softplus ->
// 12-edge node sum -> NS + BN2 partials. thread = (node, 8-ch group).
// ---------------------------------------------------------------------------
__global__ __launch_bounds__(256) void k3_msg2(
    const unsigned short* __restrict__ gated, const float* __restrict__ stats,
    float* __restrict__ NS, float* __restrict__ part2, int nNodes)
{
    const int tid = threadIdx.x;
    const int o  = tid & 15;    // ch oct: filter ch o*8..+7, core 128+o*8..+7
    const int nl = tid >> 4;    // 16 nodes per block pass
    float scF[8], shF[8], scC[8], shC[8];
    #pragma unroll
    for (int k = 0; k < 8; ++k) {
        int cf = o * 8 + k;
        scF[k] = stats[cf];        shF[k] = stats[256 + cf];
        scC[k] = stats[128 + cf];  shC[k] = stats[384 + cf];
    }
    float sA[8] = {}, s2A[8] = {};
    for (int n = blockIdx.x * 16 + nl; n < nNodes; n += gridDim.x * 16) {
        float m[8] = {};
        for (int j = 0; j < 12; ++j) {
            size_t base = (size_t)(n * 12 + j) * 256;
            uint4 uf = *(const uint4*)(gated + base + o * 8);
            uint4 uc = *(const uint4*)(gated + base + 128 + o * 8);
            unsigned fu[4] = {uf.x, uf.y, uf.z, uf.w};
            unsigned cu[4] = {uc.x, uc.y, uc.z, uc.w};
            #pragma unroll
            for (int q = 0; q < 4; ++q) {
                float f0 = fmaf(bf2f((unsigned short)(fu[q] & 0xffffu)), scF[q*2],   shF[q*2]);
                float f1 = fmaf(bf2f((unsigned short)(fu[q] >> 16)),     scF[q*2+1], shF[q*2+1]);
                float c0 = fmaf(bf2f((unsigned short)(cu[q] & 0xffffu)), scC[q*2],   shC[q*2]);
                float c1 = fmaf(bf2f((unsigned short)(cu[q] >> 16)),     scC[q*2+1], shC[q*2+1]);
                m[q*2]   = fmaf(sigmoidf(f0), softplusf(c0), m[q*2]);
                m[q*2+1] = fmaf(sigmoidf(f1), softplusf(c1), m[q*2+1]);
            }
        }
        float4 o0 = {m[0], m[1], m[2], m[3]};
        float4 o1 = {m[4], m[5], m[6], m[7]};
        *(float4*)(NS + (size_t)n * 128 + o * 8)     = o0;
        *(float4*)(NS + (size_t)n * 128 + o * 8 + 4) = o1;
        #pragma unroll
        for (int k = 0; k < 8; ++k) {
            sA[k] += m[k];
            s2A[k] = fmaf(m[k], m[k], s2A[k]);
        }
    }
    __shared__ float red[2][16][128];
    #pragma unroll
    for (int k = 0; k < 8; ++k) {
        red[0][nl][o * 8 + k] = sA[k];
        red[1][nl][o * 8 + k] = s2A[k];
    }
    __syncthreads();
    if (tid < 128) {
        float s = 0.f, s2 = 0.f;
        #pragma unroll
        for (int r = 0; r < 16; ++r) {
            s  += red[0][r][tid];
            s2 += red[1][r][tid];
        }
        part2[(size_t)blockIdx.x * 256 + tid]       = s;
        part2[(size_t)blockIdx.x * 256 + 128 + tid] = s2;
    }
}

__global__ __launch_bounds__(1024) void k3b_reduce(
    const float* __restrict__ part2, const float* __restrict__ g2v,
    const float* __restrict__ b2v, float* __restrict__ stats2,
    int nBlocks, float invN)
{
    __shared__ float4 red[16][64];
    const int cq = threadIdx.x & 63;
    const int g  = threadIdx.x >> 6;
    float4 s = {0.f, 0.f, 0.f, 0.f};
    for (int i = g; i < nBlocks; i += 16) {
        float4 v = *(const float4*)(part2 + (size_t)i * 256 + cq * 4);
        s.x += v.x; s.y += v.y; s.z += v.z; s.w += v.w;
    }
    red[g][cq] = s;
    __syncthreads();
    if (threadIdx.x < 128) {
        const int c = threadIdx.x;
        float sT = 0.f, s2T = 0.f;
        #pragma unroll
        for (int w = 0; w < 16; ++w) {
            const float* r = (const float*)&red[w][0];
            sT  += r[c];
            s2T += r[128 + c];
        }
        float mean = sT * invN;
        float var = fmaf(-mean, mean, s2T * invN);
        float sc = g2v[c] * rsqrtf(var + 1e-5f);
        stats2[c] = sc;
        stats2[128 + c] = fmaf(-mean, sc, b2v[c]);
    }
}

// ---------------------------------------------------------------------------
// K4: out = softplus(x + nbr_sumed*scale2 + shift2)
// ---------------------------------------------------------------------------
__global__ __launch_bounds__(256) void k4_final(
    const float* __restrict__ x, const float* __restrict__ ns,
    const float* __restrict__ stats2, float* __restrict__ out, int total4)
{
    int idx = blockIdx.x * 256 + threadIdx.x;
    for (int i = idx; i < total4; i += gridDim.x * 256) {
        int cq = i & 31;
        float4 xv = ((const float4*)x)[i];
        float4 sv = ((const float4*)ns)[i];
        float4 sc = ((const float4*)stats2)[cq];
        float4 sh = ((const float4*)(stats2 + 128))[cq];
        float4 o;
        o.x = softplusf(fmaf(sv.x, sc.x, sh.x) + xv.x);
        o.y = softplusf(fmaf(sv.y, sc.y, sh.y) + xv.y);
        o.z = softplusf(fmaf(sv.z, sc.z, sh.z) + xv.z);
        o.w = softplusf(fmaf(sv.w, sc.w, sh.w) + xv.w);
        ((float4*)out)[i] = o;
    }
}

extern "C" void kernel_launch(void* const* d_in, const int* in_sizes, int n_in,
                              void* d_out, int out_size, void* d_ws, size_t ws_size,
                              hipStream_t stream)
{
    const float* x   = (const float*)d_in[0];
    const int*   ei  = (const int*)d_in[1];
    const float* ea  = (const float*)d_in[2];
    const float* W   = (const float*)d_in[3];
    const float* b   = (const float*)d_in[4];
    const float* g1v = (const float*)d_in[5];
    const float* b1v = (const float*)d_in[6];
    const float* g2v = (const float*)d_in[7];
    const float* b2v = (const float*)d_in[8];
    float* out = (float*)d_out;

    const int nNodes = in_sizes[0] / ATOM_FEA;
    const int nEdges = in_sizes[1] / 2;

    float* ws = (float*)d_ws;
    float* A   = ws;                                // nNodes*256
    float* Bm  = A   + (size_t)nNodes * 256;        // nNodes*256
    float* NS  = Bm  + (size_t)nNodes * 256;        // nNodes*128
    float* P1  = NS  + (size_t)nNodes * 128;        // GRID_G*512
    float* P2  = P1  + (size_t)GRID_G * 512;        // GRID_G*256
    float* S1  = P2  + (size_t)GRID_G * 256;        // 512
    float* S2  = S1  + 512;                         // 256
    unsigned short* gated = (unsigned short*)(S2 + 256);  // nEdges*256 bf16
    (void)ws_size; (void)n_in; (void)out_size;

    dim3 grid1(8, (nNodes + 63) / 64);
    k1_nodegemm<<<grid1, 256, 0, stream>>>(x, W, A, Bm, nNodes);

    k2_fused<<<GRID_G, 256, 0, stream>>>(A, Bm, ea, ei, W, b, gated, P1, nNodes, nEdges);
    k2b_reduce<<<1, 1024, 0, stream>>>(P1, g1v, b1v, S1, GRID_G, 1.f / (float)nEdges);
    k3_msg2<<<GRID_G, 256, 0, stream>>>(gated, S1, NS, P2, nNodes);
    k3b_reduce<<<1, 1024, 0, stream>>>(P2, g2v, b2v, S2, GRID_G, 1.f / (float)nNodes);
    k4_final<<<2048, 256, 0, stream>>>(x, NS, S2, out, nNodes * 32);
}

// Round 5
// 656.154 us; speedup vs baseline: 2.9028x; 1.0291x over previous
//
#include <hip/hip_runtime.h>
#include <math.h>

#define ATOM_FEA 128
#define NBR_FEA  64
#define IN_DIM   320   // 2*ATOM_FEA + NBR_FEA
#define OUT_DIM  256   // 2*ATOM_FEA

#define M_TILE   48    // edges per tile = exactly 4 nodes (48 = 4*12)
#define GRID_G   768   // k2 persistent grid: 3 blocks/CU resident
#define GRID_3   1024  // k3 grid
#define RB1      32    // stage-1 reduce blocks

typedef float  f32x4 __attribute__((ext_vector_type(4)));
typedef short  s16x8 __attribute__((ext_vector_type(8)));   // 8 bf16

__device__ __forceinline__ float softplusf(float v) {
    float e = __expf(-fabsf(v));
    return fmaxf(v, 0.f) + __logf(1.f + e);
}
__device__ __forceinline__ float sigmoidf(float v) {
    return __builtin_amdgcn_rcpf(1.f + __expf(-v));
}
__device__ __forceinline__ unsigned short f2bf(float f) {   // RNE f32->bf16
    unsigned u = __float_as_uint(f);
    return (unsigned short)((u + 0x7FFFu + ((u >> 16) & 1u)) >> 16);
}
__device__ __forceinline__ float bf2f(unsigned short h) {
    return __uint_as_float(((unsigned)h) << 16);
}
__device__ __forceinline__ unsigned pk2(float a, float b) {
    return (unsigned)f2bf(a) | ((unsigned)f2bf(b) << 16);
}

// LDS layout for k2_fused:
#define EA_OFF   0
#define EA_STR   144     // 48 rows ea tile (72 bf16)
#define X_OFF    6912
#define X_STR    520     // 48 rows exchange (256 bf16 + pad)
#define SMEM2    31872

// ---------------------------------------------------------------------------
// K1 (MFMA): A[n,c]=W[c,0:128]·x[n], B[n,c]=W[c,128:256]·x[n], bf16 out.
// Block tile: 64 nodes x 64 outs; wave = 16 nodes x 64 outs; K=128.
// ---------------------------------------------------------------------------
__global__ __launch_bounds__(256) void k1_mfma(
    const float* __restrict__ x, const float* __restrict__ W,
    unsigned short* __restrict__ Abf, unsigned short* __restrict__ Bbf,
    int nNodes)
{
    __shared__ alignas(16) char sx[64 * 272];   // 64 rows x 128 bf16 (256B) + 16B pad
    const int tid  = threadIdx.x;
    const int wave = tid >> 6;
    const int lane = tid & 63;
    const int li   = lane & 15;
    const int quad = lane >> 4;
    const int cTile = blockIdx.x * 64;          // 0..448
    const int nTile = blockIdx.y * 64;
    const int cOff  = (cTile < 256) ? cTile : (cTile - 256);
    const int kBase = (cTile < 256) ? 0 : 128;
    unsigned short* dst = (cTile < 256) ? Abf : Bbf;

    // B fragments from W (fp32 -> bf16), once per block
    s16x8 bf[4][4];
    #pragma unroll
    for (int ks = 0; ks < 4; ++ks)
        #pragma unroll
        for (int ns = 0; ns < 4; ++ns) {
            const float* wr = W + (size_t)(cOff + ns * 16 + li) * IN_DIM + kBase + ks * 32 + quad * 8;
            float4 va = *(const float4*)wr;
            float4 vb = *(const float4*)(wr + 4);
            union { uint4 u; s16x8 v; } cv;
            cv.u = make_uint4(pk2(va.x, va.y), pk2(va.z, va.w),
                              pk2(vb.x, vb.y), pk2(vb.z, vb.w));
            bf[ks][ns] = cv.v;
        }

    // stage x tile (fp32 -> bf16): 64 rows x 128 floats = 2048 float4
    #pragma unroll
    for (int i = 0; i < 8; ++i) {
        int idx = tid + i * 256;        // 0..2047 = 64 rows x 32 quads
        int r = idx >> 5, q = idx & 31;
        int gn = nTile + r;
        float4 v = make_float4(0.f, 0.f, 0.f, 0.f);
        if (gn < nNodes) v = *(const float4*)(x + (size_t)gn * ATOM_FEA + q * 4);
        uint2 u; u.x = pk2(v.x, v.y); u.y = pk2(v.z, v.w);
        *(uint2*)(sx + r * 272 + q * 8) = u;
    }
    __syncthreads();

    s16x8 af[4];
    #pragma unroll
    for (int ks = 0; ks < 4; ++ks)
        af[ks] = *(const s16x8*)(sx + (wave * 16 + li) * 272 + (ks * 32 + quad * 8) * 2);

    f32x4 acc[4] = {};
    #pragma unroll
    for (int ks = 0; ks < 4; ++ks)
        #pragma unroll
        for (int ns = 0; ns < 4; ++ns)
            acc[ns] = __builtin_amdgcn_mfma_f32_16x16x32_bf16(af[ks], bf[ks][ns], acc[ns], 0, 0, 0);

    #pragma unroll
    for (int ns = 0; ns < 4; ++ns)
        #pragma unroll
        for (int r = 0; r < 4; ++r) {
            int node = nTile + wave * 16 + quad * 4 + r;
            if (node < nNodes)
                dst[(size_t)node * 256 + cOff + ns * 16 + li] = f2bf(acc[ns][r]);
        }
}

// ---------------------------------------------------------------------------
// K2: MFMA edge-GEMM (We*ea) -> LDS exchange -> clean-layout epilogue:
// gated = X + A[nbr] + B[node] + b (A/B bf16), store bf16 gated, BN1 partials.
// ---------------------------------------------------------------------------
__global__ __launch_bounds__(256) void k2_fused(
    const unsigned short* __restrict__ Abf, const unsigned short* __restrict__ Bbf,
    const float* __restrict__ ea, const int* __restrict__ ei,
    const float* __restrict__ W, const float* __restrict__ bvec,
    unsigned short* __restrict__ gated, float* __restrict__ part,
    int nNodes, int nEdges)
{
    __shared__ alignas(16) char smem[SMEM2];
    const int tid  = threadIdx.x;
    const int wave = tid >> 6;
    const int lane = tid & 63;
    const int li   = lane & 15;
    const int quad = lane >> 4;

    // W (We^T) fragments straight from global, packed bf16
    s16x8 bfr[2][4];
    #pragma unroll
    for (int ks = 0; ks < 2; ++ks)
        #pragma unroll
        for (int ns = 0; ns < 4; ++ns) {
            int chn = wave * 64 + ns * 16 + li;
            const float* wr = W + (size_t)chn * IN_DIM + 256 + ks * 32 + quad * 8;
            float4 va = *(const float4*)wr;
            float4 vb = *(const float4*)(wr + 4);
            union { uint4 u; s16x8 v; } cv;
            cv.u = make_uint4(pk2(va.x, va.y), pk2(va.z, va.w),
                              pk2(vb.x, vb.y), pk2(vb.z, vb.w));
            bfr[ks][ns] = cv.v;
        }

    const int chq = lane;                              // phase-2: ch quad id
    const float4 b4 = *(const float4*)(bvec + chq * 4);
    float4 s4  = {0.f, 0.f, 0.f, 0.f};
    float4 s24 = {0.f, 0.f, 0.f, 0.f};

    const int nTiles = (nEdges + M_TILE - 1) / M_TILE;
    for (int t = blockIdx.x; t < nTiles; t += gridDim.x) {
        const int tBase = t * M_TILE;
        #pragma unroll
        for (int i = 0; i < 3; ++i) {
            int idx = tid + i * 256;
            int r = idx >> 4, q = idx & 15;
            int ge = tBase + r;
            float4 v = make_float4(0.f, 0.f, 0.f, 0.f);
            if (ge < nEdges) v = *(const float4*)(ea + (size_t)ge * 64 + q * 4);
            uint2 u; u.x = pk2(v.x, v.y); u.y = pk2(v.z, v.w);
            *(uint2*)(smem + EA_OFF + r * EA_STR + q * 8) = u;
        }
        __syncthreads();   // B1 (also fences prev-iter X reads)

        s16x8 af[2][3];
        #pragma unroll
        for (int ks = 0; ks < 2; ++ks)
            #pragma unroll
            for (int ms = 0; ms < 3; ++ms)
                af[ks][ms] = *(const s16x8*)(smem + EA_OFF + (ms * 16 + li) * EA_STR + (ks * 32 + quad * 8) * 2);

        f32x4 acc[3][4] = {};
        #pragma unroll
        for (int ks = 0; ks < 2; ++ks)
            #pragma unroll
            for (int ms = 0; ms < 3; ++ms)
                #pragma unroll
                for (int ns = 0; ns < 4; ++ns)
                    acc[ms][ns] = __builtin_amdgcn_mfma_f32_16x16x32_bf16(
                        af[ks][ms], bfr[ks][ns], acc[ms][ns], 0, 0, 0);

        #pragma unroll
        for (int ms = 0; ms < 3; ++ms)
            #pragma unroll
            for (int ns = 0; ns < 4; ++ns) {
                int col = wave * 64 + ns * 16 + li;
                #pragma unroll
                for (int r = 0; r < 4; ++r) {
                    int row = ms * 16 + quad * 4 + r;
                    *(unsigned short*)(smem + X_OFF + row * X_STR + col * 2) = f2bf(acc[ms][ns][r]);
                }
            }
        __syncthreads();   // B2

        // phase 2: wave owns node (t*4 + wave); lanes cover 256 ch (4 each)
        const int node = t * 4 + wave;
        if (node < nNodes) {
            uint2 bn2 = *(const uint2*)(Bbf + (size_t)node * 256 + chq * 4);
            const float Bn0 = bf2f((unsigned short)(bn2.x & 0xffffu));
            const float Bn1 = bf2f((unsigned short)(bn2.x >> 16));
            const float Bn2 = bf2f((unsigned short)(bn2.y & 0xffffu));
            const float Bn3 = bf2f((unsigned short)(bn2.y >> 16));
            const int e0 = tBase + wave * 12;
            #pragma unroll
            for (int j = 0; j < 12; ++j) {
                const int e = e0 + j;
                const int nb = ei[nEdges + e];   // wave-uniform
                uint2 a2 = *(const uint2*)(Abf + (size_t)nb * 256 + chq * 4);
                uint2 xv = *(const uint2*)(smem + X_OFF + (wave * 12 + j) * X_STR + chq * 8);
                float g0 = bf2f((unsigned short)(xv.x & 0xffffu)) + bf2f((unsigned short)(a2.x & 0xffffu)) + Bn0 + b4.x;
                float g1 = bf2f((unsigned short)(xv.x >> 16))     + bf2f((unsigned short)(a2.x >> 16))     + Bn1 + b4.y;
                float g2 = bf2f((unsigned short)(xv.y & 0xffffu)) + bf2f((unsigned short)(a2.y & 0xffffu)) + Bn2 + b4.z;
                float g3 = bf2f((unsigned short)(xv.y >> 16))     + bf2f((unsigned short)(a2.y >> 16))     + Bn3 + b4.w;
                s4.x += g0; s4.y += g1; s4.z += g2; s4.w += g3;
                s24.x = fmaf(g0, g0, s24.x); s24.y = fmaf(g1, g1, s24.y);
                s24.z = fmaf(g2, g2, s24.z); s24.w = fmaf(g3, g3, s24.w);
                uint2 o; o.x = pk2(g0, g1); o.y = pk2(g2, g3);
                *(uint2*)(gated + (size_t)e * 256 + chq * 4) = o;
            }
        }
    }

    // block-level BN1 partial reduce
    __syncthreads();
    float* red = (float*)smem;
    *(float4*)(red + (size_t)(wave * 64 + chq) * 8)     = s4;
    *(float4*)(red + (size_t)(wave * 64 + chq) * 8 + 4) = s24;
    __syncthreads();
    {
        const int c = tid;
        const int g = c >> 2, k = c & 3;
        float s = 0.f, s2 = 0.f;
        #pragma unroll
        for (int w = 0; w < 4; ++w) {
            s  += red[(w * 64 + g) * 8 + k];
            s2 += red[(w * 64 + g) * 8 + 4 + k];
        }
        part[(size_t)blockIdx.x * 512 + c]       = s;
        part[(size_t)blockIdx.x * 512 + 256 + c] = s2;
    }
}

// ---- two-stage BN1 reduce -------------------------------------------------
__global__ __launch_bounds__(512) void k2b1(
    const float* __restrict__ part, float* __restrict__ out, int nRows, int rowsPerBlk)
{
    const int c = threadIdx.x;
    int r0 = blockIdx.x * rowsPerBlk;
    int r1 = min(r0 + rowsPerBlk, nRows);
    float s = 0.f;
    for (int r = r0; r < r1; ++r) s += part[(size_t)r * 512 + c];
    out[(size_t)blockIdx.x * 512 + c] = s;
}
__global__ __launch_bounds__(256) void k2b2(
    const float* __restrict__ p1, const float* __restrict__ g1v,
    const float* __restrict__ b1v, float* __restrict__ stats, float invE)
{
    const int c = threadIdx.x;
    float s = 0.f, s2 = 0.f;
    for (int r = 0; r < RB1; ++r) {
        s  += p1[(size_t)r * 512 + c];
        s2 += p1[(size_t)r * 512 + 256 + c];
    }
    float mean = s * invE;
    float var = fmaf(-mean, mean, s2 * invE);
    float sc = g1v[c] * rsqrtf(var + 1e-5f);
    stats[c] = sc;
    stats[256 + c] = fmaf(-mean, sc, b1v[c]);
}

// ---------------------------------------------------------------------------
// K3: elementwise over stored bf16 gated: BN1 affine -> sigmoid*softplus ->
// 12-edge node sum -> NS + BN2 partials.
// ---------------------------------------------------------------------------
__global__ __launch_bounds__(256) void k3_msg2(
    const unsigned short* __restrict__ gated, const float* __restrict__ stats,
    float* __restrict__ NS, float* __restrict__ part2, int nNodes)
{
    const int tid = threadIdx.x;
    const int o  = tid & 15;
    const int nl = tid >> 4;
    float scF[8], shF[8], scC[8], shC[8];
    #pragma unroll
    for (int k = 0; k < 8; ++k) {
        int cf = o * 8 + k;
        scF[k] = stats[cf];        shF[k] = stats[256 + cf];
        scC[k] = stats[128 + cf];  shC[k] = stats[384 + cf];
    }
    float sA[8] = {}, s2A[8] = {};
    for (int n = blockIdx.x * 16 + nl; n < nNodes; n += gridDim.x * 16) {
        float m[8] = {};
        for (int j = 0; j < 12; ++j) {
            size_t base = (size_t)(n * 12 + j) * 256;
            uint4 uf = *(const uint4*)(gated + base + o * 8);
            uint4 uc = *(const uint4*)(gated + base + 128 + o * 8);
            unsigned fu[4] = {uf.x, uf.y, uf.z, uf.w};
            unsigned cu[4] = {uc.x, uc.y, uc.z, uc.w};
            #pragma unroll
            for (int q = 0; q < 4; ++q) {
                float f0 = fmaf(bf2f((unsigned short)(fu[q] & 0xffffu)), scF[q*2],   shF[q*2]);
                float f1 = fmaf(bf2f((unsigned short)(fu[q] >> 16)),     scF[q*2+1], shF[q*2+1]);
                float c0 = fmaf(bf2f((unsigned short)(cu[q] & 0xffffu)), scC[q*2],   shC[q*2]);
                float c1 = fmaf(bf2f((unsigned short)(cu[q] >> 16)),     scC[q*2+1], shC[q*2+1]);
                m[q*2]   = fmaf(sigmoidf(f0), softplusf(c0), m[q*2]);
                m[q*2+1] = fmaf(sigmoidf(f1), softplusf(c1), m[q*2+1]);
            }
        }
        float4 o0 = {m[0], m[1], m[2], m[3]};
        float4 o1 = {m[4], m[5], m[6], m[7]};
        *(float4*)(NS + (size_t)n * 128 + o * 8)     = o0;
        *(float4*)(NS + (size_t)n * 128 + o * 8 + 4) = o1;
        #pragma unroll
        for (int k = 0; k < 8; ++k) {
            sA[k] += m[k];
            s2A[k] = fmaf(m[k], m[k], s2A[k]);
        }
    }
    __shared__ float red[2][16][128];
    #pragma unroll
    for (int k = 0; k < 8; ++k) {
        red[0][nl][o * 8 + k] = sA[k];
        red[1][nl][o * 8 + k] = s2A[k];
    }
    __syncthreads();
    if (tid < 128) {
        float s = 0.f, s2 = 0.f;
        #pragma unroll
        for (int r = 0; r < 16; ++r) {
            s  += red[0][r][tid];
            s2 += red[1][r][tid];
        }
        part2[(size_t)blockIdx.x * 256 + tid]       = s;
        part2[(size_t)blockIdx.x * 256 + 128 + tid] = s2;
    }
}

// ---- two-stage BN2 reduce -------------------------------------------------
__global__ __launch_bounds__(256) void k3b1(
    const float* __restrict__ part2, float* __restrict__ out, int nRows, int rowsPerBlk)
{
    const int c = threadIdx.x;
    int r0 = blockIdx.x * rowsPerBlk;
    int r1 = min(r0 + rowsPerBlk, nRows);
    float s = 0.f;
    for (int r = r0; r < r1; ++r) s += part2[(size_t)r * 256 + c];
    out[(size_t)blockIdx.x * 256 + c] = s;
}
__global__ __launch_bounds__(128) void k3b2(
    const float* __restrict__ p1, const float* __restrict__ g2v,
    const float* __restrict__ b2v, float* __restrict__ stats2, float invN)
{
    const int c = threadIdx.x;
    float s = 0.f, s2 = 0.f;
    for (int r = 0; r < RB1; ++r) {
        s  += p1[(size_t)r * 256 + c];
        s2 += p1[(size_t)r * 256 + 128 + c];
    }
    float mean = s * invN;
    float var = fmaf(-mean, mean, s2 * invN);
    float sc = g2v[c] * rsqrtf(var + 1e-5f);
    stats2[c] = sc;
    stats2[128 + c] = fmaf(-mean, sc, b2v[c]);
}

// ---------------------------------------------------------------------------
// K4: out = softplus(x + nbr_sumed*scale2 + shift2)
// ---------------------------------------------------------------------------
__global__ __launch_bounds__(256) void k4_final(
    const float* __restrict__ x, const float* __restrict__ ns,
    const float* __restrict__ stats2, float* __restrict__ out, int total4)
{
    int idx = blockIdx.x * 256 + threadIdx.x;
    for (int i = idx; i < total4; i += gridDim.x * 256) {
        int cq = i & 31;
        float4 xv = ((const float4*)x)[i];
        float4 sv = ((const float4*)ns)[i];
        float4 sc = ((const float4*)stats2)[cq];
        float4 sh = ((const float4*)(stats2 + 128))[cq];
        float4 o;
        o.x = softplusf(fmaf(sv.x, sc.x, sh.x) + xv.x);
        o.y = softplusf(fmaf(sv.y, sc.y, sh.y) + xv.y);
        o.z = softplusf(fmaf(sv.z, sc.z, sh.z) + xv.z);
        o.w = softplusf(fmaf(sv.w, sc.w, sh.w) + xv.w);
        ((float4*)out)[i] = o;
    }
}

extern "C" void kernel_launch(void* const* d_in, const int* in_sizes, int n_in,
                              void* d_out, int out_size, void* d_ws, size_t ws_size,
                              hipStream_t stream)
{
    const float* x   = (const float*)d_in[0];
    const int*   ei  = (const int*)d_in[1];
    const float* ea  = (const float*)d_in[2];
    const float* W   = (const float*)d_in[3];
    const float* b   = (const float*)d_in[4];
    const float* g1v = (const float*)d_in[5];
    const float* b1v = (const float*)d_in[6];
    const float* g2v = (const float*)d_in[7];
    const float* b2v = (const float*)d_in[8];
    float* out = (float*)d_out;

    const int nNodes = in_sizes[0] / ATOM_FEA;
    const int nEdges = in_sizes[1] / 2;

    unsigned short* Abf   = (unsigned short*)d_ws;               // nNodes*256 bf16
    unsigned short* Bbf   = Abf + (size_t)nNodes * 256;          // nNodes*256 bf16
    unsigned short* gated = Bbf + (size_t)nNodes * 256;          // nEdges*256 bf16
    float* NS  = (float*)(gated + (size_t)nEdges * 256);         // nNodes*128
    float* P1  = NS  + (size_t)nNodes * 128;                     // GRID_G*512
    float* P1b = P1  + (size_t)GRID_G * 512;                     // RB1*512
    float* P2  = P1b + (size_t)RB1 * 512;                        // GRID_3*256
    float* P2b = P2  + (size_t)GRID_3 * 256;                     // RB1*256
    float* S1  = P2b + (size_t)RB1 * 256;                        // 512
    float* S2  = S1 + 512;                                       // 256
    (void)ws_size; (void)n_in; (void)out_size;

    dim3 grid1(8, (nNodes + 63) / 64);
    k1_mfma<<<grid1, 256, 0, stream>>>(x, W, Abf, Bbf, nNodes);

    k2_fused<<<GRID_G, 256, 0, stream>>>(Abf, Bbf, ea, ei, W, b, gated, P1, nNodes, nEdges);
    k2b1<<<RB1, 512, 0, stream>>>(P1, P1b, GRID_G, (GRID_G + RB1 - 1) / RB1);
    k2b2<<<1, 256, 0, stream>>>(P1b, g1v, b1v, S1, 1.f / (float)nEdges);
    k3_msg2<<<GRID_3, 256, 0, stream>>>(gated, S1, NS, P2, nNodes);
    k3b1<<<RB1, 256, 0, stream>>>(P2, P2b, GRID_3, (GRID_3 + RB1 - 1) / RB1);
    k3b2<<<1, 128, 0, stream>>>(P2b, g2v, b2v, S2, 1.f / (float)nNodes);
    k4_final<<<2048, 256, 0, stream>>>(x, NS, S2, out, nNodes * 32);
}